// Round 16
// baseline (76.903 us; speedup 1.0000x reference)
//
#include <hip/hip_runtime.h>
#include <stdint.h>

typedef float  f32x4 __attribute__((ext_vector_type(4)));
typedef short  s16x8 __attribute__((ext_vector_type(8)));
typedef unsigned int u32;
typedef u32    u32x2 __attribute__((ext_vector_type(2)));
typedef u32    u32x4 __attribute__((ext_vector_type(4)));
typedef unsigned short u16;

#define MFMA16(a,b,c) __builtin_amdgcn_mfma_f32_16x16x32_bf16((a),(b),(c),0,0,0)

__device__ __forceinline__ u16 f2bf(float f){
  u32 u = __float_as_uint(f);
  return (u16)((u + 0x7fffu + ((u >> 16) & 1u)) >> 16);   // RNE
}
__device__ __forceinline__ float bf2f(u16 h){ return __uint_as_float(((u32)h) << 16); }
__device__ __forceinline__ u32 pack2bf(float a, float b){ return (u32)f2bf(a) | ((u32)f2bf(b) << 16); }
// truncation pack (round-to-zero): fine for P in [0,1]
__device__ __forceinline__ u32 packtrunc(float a, float b){
  return (__float_as_uint(a) >> 16) | (__float_as_uint(b) & 0xffff0000u);
}
__device__ __forceinline__ f32x4 f4zero(){ f32x4 z; z[0]=0.f; z[1]=0.f; z[2]=0.f; z[3]=0.f; return z; }
// register-only vector build (NO union: unions can defeat SROA -> scratch)
__device__ __forceinline__ s16x8 mk8(u32 a, u32 b, u32 c, u32 d){
  u32x4 w; w[0]=a; w[1]=b; w[2]=c; w[3]=d;
  return __builtin_bit_cast(s16x8, w);
}

// async global->LDS, 16B per lane; LDS dest is wave-uniform base + lane*16
__device__ __forceinline__ void async16(const void* g, void* l){
  __builtin_amdgcn_global_load_lds(
      (const __attribute__((address_space(1))) unsigned int*)g,
      (__attribute__((address_space(3))) unsigned int*)l, 16, 0, 0);
}

// ---------------------------------------------------------------------------
// K1 mega-prep, fully fused (verified round 15). Block ranges:
//   [0,8): w1^T bf16; [8,264): ygemm + x-split (xh/xl) + Xt emission.
//   x is read from HBM exactly ONCE per element.
// ---------------------------------------------------------------------------
__global__ __launch_bounds__(256) void k_prep(
    const float* __restrict__ x, const float* __restrict__ wr, const float* __restrict__ w1,
    u16* __restrict__ xh, u16* __restrict__ xl, u16* __restrict__ Xt,
    u16* __restrict__ w1t, u16* __restrict__ yh, u16* __restrict__ yl)
{
  __shared__ __align__(16) char smem[65536];
  const int tid = threadIdx.x, bid = blockIdx.x;

  if (bid < 8){
    const int base = bid * 2048;
#pragma unroll
    for (int k = 0; k < 8; k++){
      int idx = base + k*256 + tid;
      int c = idx >> 7, f = idx & 127;
      w1t[idx] = f2bf(w1[f*128 + c]);            // w1T[c][f] = w1[f][c]
    }
    return;
  }
  // ---- fused ygemm/x-split: 256 blocks x 256 thr (4 warps), 64 rows ----
  u16* sbh = (u16*)smem;                         // wr^T hi swizzled, 32 KB
  u16* sbl = sbh + 16384;                        // wr^T lo swizzled, 32 KB
  {
    const int c = tid & 127, f0 = (tid >> 7) * 64;
    const int key = (c & 7) << 4;
#pragma unroll
    for (int fi = 0; fi < 64; fi += 2){
      int f = f0 + fi;
      float v0 = wr[f*128 + c], v1 = wr[(f+1)*128 + c];
      u16 h0 = f2bf(v0), h1 = f2bf(v1);
      u32 hw = (u32)h0 | ((u32)h1 << 16);
      u32 lw = (u32)f2bf(v0 - bf2f(h0)) | ((u32)f2bf(v1 - bf2f(h1)) << 16);
      int byte = c*256 + ((((2*f) & ~15) ^ key) + ((2*f) & 15));
      *(u32*)((char*)sbh + byte) = hw;
      *(u32*)((char*)sbl + byte) = lw;
    }
  }
  __syncthreads();
  const int w = tid >> 6, lane = tid & 63, lr = lane & 15, g = lane >> 4;
  const int bidp = bid - 8;
  const long rowbase = (long)bidp * 64;
  s16x8 ah[4], al[4];
#pragma unroll
  for (int kc = 0; kc < 4; kc++){
    long r = rowbase + w*16 + lr;
    const float4* px = (const float4*)(x + r*128 + kc*32 + g*8);
    float4 a = px[0], bV = px[1];
    u32 hh0, hh1, hh2, hh3, ll0, ll1, ll2, ll3;
    { u16 p=f2bf(a.x), q=f2bf(a.y); hh0=(u32)p|((u32)q<<16);
      ll0=(u32)f2bf(a.x-bf2f(p))|((u32)f2bf(a.y-bf2f(q))<<16); }
    { u16 p=f2bf(a.z), q=f2bf(a.w); hh1=(u32)p|((u32)q<<16);
      ll1=(u32)f2bf(a.z-bf2f(p))|((u32)f2bf(a.w-bf2f(q))<<16); }
    { u16 p=f2bf(bV.x), q=f2bf(bV.y); hh2=(u32)p|((u32)q<<16);
      ll2=(u32)f2bf(bV.x-bf2f(p))|((u32)f2bf(bV.y-bf2f(q))<<16); }
    { u16 p=f2bf(bV.z), q=f2bf(bV.w); hh3=(u32)p|((u32)q<<16);
      ll3=(u32)f2bf(bV.z-bf2f(p))|((u32)f2bf(bV.w-bf2f(q))<<16); }
    ah[kc] = mk8(hh0,hh1,hh2,hh3);
    al[kc] = mk8(ll0,ll1,ll2,ll3);
  }
  f32x4 acc[8];
#pragma unroll
  for (int cg = 0; cg < 8; cg++) acc[cg] = f4zero();
  const int swz = (lr & 7) << 4;
#pragma unroll
  for (int cg = 0; cg < 8; cg++){
    const int rowt = (cg*16 + lr) * 256;
#pragma unroll
    for (int kc = 0; kc < 4; kc++){
      int boff = rowt + ((kc*64 + g*16) ^ swz);
      s16x8 bh = *(const s16x8*)((const char*)sbh + boff);
      s16x8 bl = *(const s16x8*)((const char*)sbl + boff);
      acc[cg] = MFMA16(ah[kc], bh, acc[cg]);
      acc[cg] = MFMA16(al[kc], bh, acc[cg]);
      acc[cg] = MFMA16(ah[kc], bl, acc[cg]);
    }
  }
#pragma unroll
  for (int cg = 0; cg < 8; cg++)
#pragma unroll
    for (int r = 0; r < 4; r++){
      long q = rowbase + w*16 + 4*g + r;       // C-layout: row=4g+r, col=lr
      int  c = cg*16 + lr;
      float v = acc[cg][r] * 1.4426950408889634f;
      u16 h = f2bf(v);
      yh[q*128 + c] = h;
      yl[q*128 + c] = f2bf(v - bf2f(h));
    }
  // ---- Phase C: fragments -> LDS x-tile [64][128] (swizzled) ----
  __syncthreads();                               // wr tables fully consumed
#pragma unroll
  for (int kc = 0; kc < 4; kc++){
    int off = (w*16 + lr)*256 + ((kc*64 + g*16) ^ swz);
    *(s16x8*)(smem + off)         = ah[kc];
    *(s16x8*)(smem + 16384 + off) = al[kc];
  }
  __syncthreads();
  // ---- Phase D: coalesced xh/xl emission ----
  {
    char* gbh = (char*)xh + rowbase*256;
    char* gbl = (char*)xl + rowbase*256;
#pragma unroll
    for (int it = 0; it < 4; it++){
      int off = (tid + it*256)*16;
      int row = off >> 8;
      int so = off ^ ((row & 7) << 4);
      *(s16x8*)(gbh + off) = *(const s16x8*)(smem + so);
      *(s16x8*)(gbl + off) = *(const s16x8*)(smem + 16384 + so);
    }
  }
  // ---- Phase E: Xt transpose emission (thread = (d, n-half)) ----
  {
    const int b  = bidp >> 5;
    const int n0 = (bidp & 31) * 64;
    const int d  = tid >> 1, nh = tid & 1;
    u16 tmp[32];
#pragma unroll
    for (int j = 0; j < 32; j++){
      int n = nh*32 + j;
      int byte = n*256 + ((((d >> 3) << 4) ^ ((n & 7) << 4))) + (d & 7)*2;
      tmp[j] = *(const u16*)(smem + byte);
    }
    u16* dst = Xt + (long)b*262144 + (long)d*2048 + n0 + nh*32;
#pragma unroll
    for (int j2 = 0; j2 < 4; j2++){
      s16x8 v = mk8((u32)tmp[j2*8+0] | ((u32)tmp[j2*8+1] << 16),
                    (u32)tmp[j2*8+2] | ((u32)tmp[j2*8+3] << 16),
                    (u32)tmp[j2*8+4] | ((u32)tmp[j2*8+5] << 16),
                    (u32)tmp[j2*8+6] | ((u32)tmp[j2*8+7] << 16));
      *(s16x8*)(dst + j2*8) = v;
    }
  }
}

// ---------------------------------------------------------------------------
// K3: fused flash, 8-warp (verified body). This round: S-accumulators split
//   into 2 independent chains per kv-half (kc 0-1 / kc 2-3) to halve the
//   dependent-MFMA latency chain; merged by one f32x4 add before softmax.
//   max tree shaped for v_max3 fusion. No sync/layout changes.
//   NO launch_bounds min-wave cap (spill rule: rounds 2/4/6).
// ---------------------------------------------------------------------------
__global__ __launch_bounds__(512) void k_flash(
    const u16* __restrict__ xh, const u16* __restrict__ xl, const u16* __restrict__ Xt,
    const u16* __restrict__ yh, const u16* __restrict__ yl,
    u16* __restrict__ Opart, float* __restrict__ mpart, float* __restrict__ lpart,
    float* __restrict__ S0, int KS, int kslog)
{
  __shared__ __align__(16) char lds[49152];
  const int tid = threadIdx.x, bid = blockIdx.x;
  const int b     = bid & 7;                   // XCD b owns batch b
  const int inner = bid >> 3;
  const int s     = inner & (KS - 1);
  const int qbl   = inner >> kslog;
  const int qb    = b*16 + qbl;
  const int nspan = 2048 >> kslog;
  const int kv0   = s * nspan;
  const int ntiles = nspan >> 5;
  const int w = tid >> 6, lane = tid & 63, lr = lane & 15, g = lane >> 4;
  const long qrow = (long)qb*128 + w*16;       // 16 q-rows per warp

  // ---- hoisted per-lane constants ----
  const int soff = w*1024 + lane*16;
  const int sswo = soff ^ (((soff >> 8) & 7) << 4);        // xh/xl src swz
  const int trow = soff >> 6;
  const int tsrc = trow*4096 + ((soff & 63) ^ ((trow & 3) << 4)); // xt src swz
  const int bS0 = lr*256 + (( 0 + g*16) ^ ((lr & 7) << 4));
  const int bS1 = lr*256 + (( 64 + g*16) ^ ((lr & 7) << 4));
  const int bS2 = lr*256 + ((128 + g*16) ^ ((lr & 7) << 4));
  const int bS3 = lr*256 + ((192 + g*16) ^ ((lr & 7) << 4));
  const int bPV = lr*64 + ((g*16) ^ ((lr & 3) << 4));

  // Y fragments (B-operands), hi/lo — 16 q-cols per warp
  s16x8 byh[4], byl[4];
#pragma unroll
  for (int kc = 0; kc < 4; kc++){
    long r = qrow + lr;
    byh[kc] = *(const s16x8*)(yh + r*128 + kc*32 + g*8);
    byl[kc] = *(const s16x8*)(yl + r*128 + kc*32 + g*8);
  }

  f32x4 o[8];                                  // O^T: [d-tile dg]
#pragma unroll
  for (int dg = 0; dg < 8; dg++) o[dg] = f4zero();
  float mrun = -1e30f, lrun = 0.f;

  const char* gxh  = (const char*)xh + ((long)b*2048 + kv0)*256;
  const char* gxl  = (const char*)xl + ((long)b*2048 + kv0)*256;
  const char* gxtb = (const char*)(Xt + (long)b*262144 + kv0);

  auto stage = [&](int bufi, int t){
    char* dst = lds + bufi*8192 + w*1024;      // wave-uniform dest
    async16(gxh  + (long)t*8192 + sswo, dst);
    async16(gxl  + (long)t*8192 + sswo, dst + 16384);
    async16(gxtb + (long)t*64   + tsrc, dst + 32768);
  };

  stage(0, 0);
  __syncthreads();

  for (int t = 0; t < ntiles; t++){
    const int cur = t & 1;
    const char* pb = lds + cur*8192;
    const char* a0 = pb + bS0;
    const char* a1 = pb + bS1;
    const char* a2 = pb + bS2;
    const char* a3 = pb + bS3;

    // ---- S^T tile [32kv x 16q], 3-term hi/lo, 2 indep chains per half ----
    f32x4 sA[2], sB[2];                        // [kv-half ch] x {kc01, kc23}
    sA[0] = f4zero(); sA[1] = f4zero();
    sB[0] = f4zero(); sB[1] = f4zero();
    __builtin_amdgcn_s_setprio(1);
#pragma unroll
    for (int ch = 0; ch < 2; ch++){
      const int co = ch*4096;                  // fh at co, fl at 16384+co
      s16x8 fh0, fl0, fh1, fl1;
      fh0 = *(const s16x8*)(a0 + co); fl0 = *(const s16x8*)(a0 + 16384 + co);
      fh1 = *(const s16x8*)(a2 + co); fl1 = *(const s16x8*)(a2 + 16384 + co);
      sA[ch] = MFMA16(fh0, byh[0], sA[ch]);
      sB[ch] = MFMA16(fh1, byh[2], sB[ch]);
      sA[ch] = MFMA16(fl0, byh[0], sA[ch]);
      sB[ch] = MFMA16(fl1, byh[2], sB[ch]);
      sA[ch] = MFMA16(fh0, byl[0], sA[ch]);
      sB[ch] = MFMA16(fh1, byl[2], sB[ch]);
      fh0 = *(const s16x8*)(a1 + co); fl0 = *(const s16x8*)(a1 + 16384 + co);
      fh1 = *(const s16x8*)(a3 + co); fl1 = *(const s16x8*)(a3 + 16384 + co);
      sA[ch] = MFMA16(fh0, byh[1], sA[ch]);
      sB[ch] = MFMA16(fh1, byh[3], sB[ch]);
      sA[ch] = MFMA16(fl0, byh[1], sA[ch]);
      sB[ch] = MFMA16(fl1, byh[3], sB[ch]);
      sA[ch] = MFMA16(fh0, byl[1], sA[ch]);
      sB[ch] = MFMA16(fh1, byl[3], sB[ch]);
    }
    __builtin_amdgcn_s_setprio(0);
    f32x4 sacc[2];
    sacc[0] = sA[0] + sB[0];
    sacc[1] = sA[1] + sB[1];

    // prefetch next tile AFTER the S reads (LDS pipe free during reads)
    if (t + 1 < ntiles) stage(cur ^ 1, t + 1);

    // ---- q=0 column dump -> S0 (only 32 of 512 blocks; warp 0, lr==0) ----
    if (qbl == 0 && w == 0 && lr == 0){
      float* s0p = S0 + b*2048 + kv0 + t*32 + 4*g;
#pragma unroll
      for (int ch = 0; ch < 2; ch++)
#pragma unroll
        for (int r = 0; r < 4; r++)
          s0p[ch*16 + r] = sacc[ch][r];
    }

    // ---- lane-local online softmax (q = lr lives in this lane) ----
    // nested 3-input maxes (v_max3-fusable)
    float cm = fmaxf(fmaxf(
                 fmaxf(fmaxf(sacc[0][0], sacc[0][1]), sacc[0][2]),
                 fmaxf(fmaxf(sacc[0][3], sacc[1][0]), sacc[1][1])),
                 fmaxf(sacc[1][2], sacc[1][3]));
    cm = fmaxf(cm, __shfl_xor(cm, 16, 64));
    cm = fmaxf(cm, __shfl_xor(cm, 32, 64));
    if (__any(cm > mrun + 8.f)){               // defer-max (log2 units, P<=256)
      float mn = fmaxf(mrun, cm);
      float sc = exp2f(mrun - mn);
#pragma unroll
      for (int dg = 0; dg < 8; dg++)
#pragma unroll
        for (int r = 0; r < 4; r++) o[dg][r] *= sc;
      lrun *= sc;
      mrun = mn;
    }
    float p[2][4];
#pragma unroll
    for (int ch = 0; ch < 2; ch++)
#pragma unroll
      for (int r = 0; r < 4; r++) p[ch][r] = exp2f(sacc[ch][r] - mrun);
    float ls = ((p[0][0] + p[0][1]) + (p[0][2] + p[0][3]))
             + ((p[1][0] + p[1][1]) + (p[1][2] + p[1][3]));
    ls += __shfl_xor(ls, 16, 64);
    ls += __shfl_xor(ls, 32, 64);
    lrun += ls;
    // lane (g,lr) holds P[q=lr][kv=16ch+4g+r]; B-frag needs kv=8g+j.
    s16x8 bpq;
    {
      u32 pw00 = packtrunc(p[0][0], p[0][1]);
      u32 pw01 = packtrunc(p[0][2], p[0][3]);
      u32 pw10 = packtrunc(p[1][0], p[1][1]);
      u32 pw11 = packtrunc(p[1][2], p[1][3]);
      int sA_ = ((g & 1) << 5) + lr;
      int sB_ = sA_ + 16;
      u32 a0s = (u32)__shfl((int)pw00, sA_, 64);
      u32 a1s = (u32)__shfl((int)pw01, sA_, 64);
      u32 a2s = (u32)__shfl((int)pw10, sA_, 64);
      u32 a3s = (u32)__shfl((int)pw11, sA_, 64);
      u32 b0s = (u32)__shfl((int)pw00, sB_, 64);
      u32 b1s = (u32)__shfl((int)pw01, sB_, 64);
      u32 b2s = (u32)__shfl((int)pw10, sB_, 64);
      u32 b3s = (u32)__shfl((int)pw11, sB_, 64);
      bool hi = (g >= 2);
      bpq = mk8(hi ? a2s : a0s, hi ? a3s : a1s, hi ? b2s : b0s, hi ? b3s : b1s);
    }

    // ---- O^T += Xt-frag (LDS swz) x P^T (regs) ----
    const char* ap = pb + 32768 + bPV;
    __builtin_amdgcn_s_setprio(1);
#pragma unroll
    for (int half = 0; half < 2; half++){
      s16x8 ax[4];
#pragma unroll
      for (int i = 0; i < 4; i++)
        ax[i] = *(const s16x8*)(ap + (half*4 + i)*1024);
#pragma unroll
      for (int i = 0; i < 4; i++)
        o[half*4 + i] = MFMA16(ax[i], bpq, o[half*4 + i]);
    }
    __builtin_amdgcn_s_setprio(0);
    __syncthreads();   // drains prefetch + guards buffer reuse
  }

  // ---- epilogue: split-major partials for contiguous merge reads ----
  {
    int lq = w*16 + lr;
    long bi = (long)(qbl*8 + b)*128 + lq;
    u16* op = Opart + bi*(long)(128 << kslog) + s*128;
#pragma unroll
    for (int dg = 0; dg < 8; dg++){
      u32x2 pw;
      pw[0] = pack2bf(o[dg][0], o[dg][1]);
      pw[1] = pack2bf(o[dg][2], o[dg][3]);
      *(u32x2*)(op + dg*16 + 4*g) = pw;
    }
    if (g == 0){
      mpart[bi*KS + s] = mrun;
      lpart[bi*KS + s] = lrun;
    }
  }
}

// ---------------------------------------------------------------------------
// K4 (fused merge + layer1 + a2-partial): 512 blocks x 256 thr, 32 rows each.
//   (verified round 15 body, unchanged)
// ---------------------------------------------------------------------------
__global__ __launch_bounds__(256) void k_mergeL1(
    const u16* __restrict__ Opart, const float* __restrict__ mpart, const float* __restrict__ lpart,
    const u16* __restrict__ w1t, const float* __restrict__ x,
    const float* __restrict__ S0,
    float* __restrict__ A2p, float* __restrict__ Lj, float* __restrict__ x1r0,
    int KS)
{
  __shared__ u16 sb[16384];                    // w1^T [c][f] swizzled (32KB)
  __shared__ u16 sa[4096];                     // A1 tile [32][128] swz (8KB)
  __shared__ float eS[32];
  __shared__ float redw[4][64];
  const int tid = threadIdx.x, bid = blockIdx.x;
  const int bb   = bid >> 6;                   // batch
  const int qbl  = (bid >> 2) & 15;
  const int rb   = (bid & 3) * 32;             // row offset within q-block
  const long R0  = (long)bid*32;               // global row base
#pragma unroll
  for (int k = 0; k < 8; k++){
    int off = (tid + k*256)*16;
    int row = off >> 8;
    *(s16x8*)((char*)sb + (off ^ ((row & 7) << 4))) = *(const s16x8*)((const char*)w1t + off);
  }
  if (tid < 32){
    const float* mp0 = mpart + (long)(bb*128)*KS;     // bi for (qbl=0,row 0)
    float M = -1e30f;
    for (int s = 0; s < KS; s++) M = fmaxf(M, mp0[s]);
    eS[tid] = exp2f(S0[bb*2048 + (bid & 63)*32 + tid] - M);
  }
  // merge phase: 512 granules (32 rows x 16), 2 per thread
#pragma unroll
  for (int k = 0; k < 2; k++){
    int gidx = tid + k*256;
    int lrow = gidx >> 4, gcol = gidx & 15;
    long bi = (long)(qbl*8 + bb)*128 + rb + lrow;
    const float* mp = mpart + bi*KS;
    const float* lp = lpart + bi*KS;
    float m = -1e30f;
    for (int s = 0; s < KS; s++) m = fmaxf(m, mp[s]);
    float ls = 0.f;
    float a0=0.f,a1=0.f,a2=0.f,a3=0.f,a4=0.f,a5=0.f,a6=0.f,a7=0.f;
    const u16* ob = Opart + bi*(long)(KS*128) + gcol*8;
    for (int s = 0; s < KS; s++){
      float wgt = exp2f(mp[s] - m);
      ls += lp[s] * wgt;
      u32x4 v = *(const u32x4*)(ob + s*128);
      a0 += bf2f((u16)(v[0] & 0xffff)) * wgt;  a1 += bf2f((u16)(v[0] >> 16)) * wgt;
      a2 += bf2f((u16)(v[1] & 0xffff)) * wgt;  a3 += bf2f((u16)(v[1] >> 16)) * wgt;
      a4 += bf2f((u16)(v[2] & 0xffff)) * wgt;  a5 += bf2f((u16)(v[2] >> 16)) * wgt;
      a6 += bf2f((u16)(v[3] & 0xffff)) * wgt;  a7 += bf2f((u16)(v[3] >> 16)) * wgt;
    }
    float inv = 1.f / ls;
    u32x4 pw;
    pw[0] = pack2bf(a0*inv, a1*inv); pw[1] = pack2bf(a2*inv, a3*inv);
    pw[2] = pack2bf(a4*inv, a5*inv); pw[3] = pack2bf(a6*inv, a7*inv);
    int off = lrow*256 + gcol*16;
    *(u32x4*)((char*)sa + (off ^ ((lrow & 7) << 4))) = pw;
  }
  __syncthreads();
  // GEMM phase: warp w = rowhalf (w&1) x colhalf (w>>1); 16 rows x 64 cols
  const int w = tid >> 6, lane = tid & 63, lr = lane & 15, g = lane >> 4;
  const int rowhalf = w & 1, colhalf = w >> 1;
  s16x8 aa[4];
#pragma unroll
  for (int kc = 0; kc < 4; kc++){
    int lrow = rowhalf*16 + lr;
    aa[kc] = *(const s16x8*)((const char*)sa +
               (lrow*256 + ((kc*64 + g*16) ^ ((lrow & 7) << 4))));
  }
  f32x4 acc[4];
#pragma unroll
  for (int cg = 0; cg < 4; cg++) acc[cg] = f4zero();
  const int swz = (lr & 7) << 4;
#pragma unroll
  for (int cg = 0; cg < 4; cg++){
    const int c = colhalf*64 + cg*16 + lr;
    const int rowt = c*256;
#pragma unroll
    for (int kc = 0; kc < 4; kc++){
      s16x8 bV = *(const s16x8*)((const char*)sb + rowt + ((kc*64 + g*16) ^ swz));
      acc[cg] = MFMA16(aa[kc], bV, acc[cg]);
    }
  }
  // x1 in-register; e-weighted partial column sums
  const float e0 = eS[rowhalf*16 + 4*g + 0];
  const float e1 = eS[rowhalf*16 + 4*g + 1];
  const float e2 = eS[rowhalf*16 + 4*g + 2];
  const float e3 = eS[rowhalf*16 + 4*g + 3];
  float sA2[4];
#pragma unroll
  for (int cg = 0; cg < 4; cg++){
    int c = colhalf*64 + cg*16 + lr;
    f32x4 vv;
#pragma unroll
    for (int r = 0; r < 4; r++){
      long q = R0 + rowhalf*16 + 4*g + r;
      vv[r] = fmaxf(acc[cg][r] + x[q*128 + c], 0.f);
    }
    if (((bid & 63) == 0) && rowhalf == 0 && g == 0)
      x1r0[bb*128 + c] = vv[0];                // batch row 0
    sA2[cg] = e0*vv[0] + e1*vv[1] + e2*vv[2] + e3*vv[3];
  }
#pragma unroll
  for (int cg = 0; cg < 4; cg++){
    sA2[cg] += __shfl_xor(sA2[cg], 16, 64);
    sA2[cg] += __shfl_xor(sA2[cg], 32, 64);
  }
  if (g == 0){
#pragma unroll
    for (int cg = 0; cg < 4; cg++) redw[w][cg*16 + lr] = sA2[cg];
  }
  __syncthreads();
  if (tid < 128){
    int cl = tid & 63, pair = (tid >> 6) * 2;
    A2p[(long)bid*128 + tid] = redw[pair][cl] + redw[pair + 1][cl];
  }
  if (w == 2){
    float v = (lane < 32) ? eS[lane] : 0.f;
    v += __shfl_xor(v, 1, 64);  v += __shfl_xor(v, 2, 64);
    v += __shfl_xor(v, 4, 64);  v += __shfl_xor(v, 8, 64);
    v += __shfl_xor(v, 16, 64); v += __shfl_xor(v, 32, 64);
    if (lane == 0) Lj[bid] = v;
  }
}

// K5: out = relu((A2/L) @ w2 + x1[:,0,:]) — 8 blocks (1/batch), f split 2-way
__global__ __launch_bounds__(256) void k_out(
    const float* __restrict__ A2p, const float* __restrict__ Lj,
    const float* __restrict__ w2, const float* __restrict__ x1r0,
    float* __restrict__ out)
{
  __shared__ float a2s[128];
  __shared__ float partial[128];
  __shared__ float Lsh;
  const int tid = threadIdx.x, b = blockIdx.x;
  const int f = tid & 127, h = tid >> 7;
  float s = 0.f;
  for (int jj = h*32; jj < h*32 + 32; jj++)
    s += A2p[(long)(b*64 + jj)*128 + f];
  if (h == 1) partial[f] = s;
  if (tid < 64){
    float Lp = Lj[b*64 + tid];
    Lp += __shfl_xor(Lp, 1, 64);  Lp += __shfl_xor(Lp, 2, 64);
    Lp += __shfl_xor(Lp, 4, 64);  Lp += __shfl_xor(Lp, 8, 64);
    Lp += __shfl_xor(Lp, 16, 64); Lp += __shfl_xor(Lp, 32, 64);
    if (tid == 0) Lsh = Lp;
  }
  __syncthreads();
  if (h == 0) a2s[f] = (s + partial[f]) / Lsh;
  __syncthreads();
  const int d = tid & 127, fh = tid >> 7;
  float acc = 0.f;
  for (int f2 = fh*64; f2 < fh*64 + 64; f2++)
    acc += a2s[f2] * w2[f2*128 + d];
  if (fh == 1) partial[d] = acc;
  __syncthreads();
  if (fh == 0)
    out[b*128 + d] = fmaxf(acc + partial[d] + x1r0[b*128 + d], 0.f);
}

// ---------------------------------------------------------------------------
extern "C" void kernel_launch(void* const* d_in, const int* in_sizes, int n_in,
                              void* d_out, int out_size, void* d_ws, size_t ws_size,
                              hipStream_t stream)
{
  const float* x  = (const float*)d_in[0];
  const float* w1 = (const float*)d_in[1];
  const float* w2 = (const float*)d_in[2];
  const float* wr = (const float*)d_in[3];
  float* out = (float*)d_out;
  char* ws = (char*)d_ws;

  u16*   xh      = (u16*)  (ws + 0);
  u16*   xl      = (u16*)  (ws + 4194304);
  u16*   Xt      = (u16*)  (ws + 8388608);
  u16*   yh      = (u16*)  (ws + 12582912);
  u16*   yl      = (u16*)  (ws + 16777216);
  u16*   w1t     = (u16*)  (ws + 20971520);
  float* S0      = (float*)(ws + 21004288);   // 64 KB (written by k_flash)
  float* Lj      = (float*)(ws + 21070848);   // 512 floats = 2 KB
  float* A2p     = (float*)(ws + 21072896);   // 512*128*4 = 256 KB
  float* x1r0    = (float*)(ws + 21335040);   // 4 KB
  const size_t tail = 21339136;

  int KS = 4, kslog = 2;
  // per-KS bytes: mpart 64K + lpart 64K + Opart bf16 4M
  while (KS > 1 && tail + (size_t)KS*4325376ull > ws_size){ KS >>= 1; kslog--; }
  float* mpart = (float*)(ws + tail);
  float* lpart = (float*)(ws + tail + (size_t)KS*65536);
  u16*   Opart = (u16*)  (ws + tail + (size_t)KS*131072);

  k_prep   <<<264, 256, 0, stream>>>(x, wr, w1, xh, xl, Xt, w1t, yh, yl);
  k_flash  <<<128*KS, 512, 0, stream>>>(xh, xl, Xt, yh, yl, Opart, mpart, lpart, S0, KS, kslog);
  k_mergeL1<<<512, 256, 0, stream>>>(Opart, mpart, lpart, w1t, x, S0, A2p, Lj, x1r0, KS);
  k_out    <<<8, 256, 0, stream>>>(A2p, Lj, w2, x1r0, out);
}